// Round 1
// baseline (423.102 us; speedup 1.0000x reference)
//
#include <hip/hip_runtime.h>

// Blockwise 8x8 2D orthonormal DCT:
//   x: (64, 1, 1024, 1024) fp32  ->  out: (64, 64, 128, 128) fp32
//   out[n][i*8+j][gi][gj] = sum_{k,l} A[i][k] * x[n][0][gi*8+k][gj*8+l] * A[j][l]
//
// Memory-bound (512 MB traffic, ~2.1 GFLOP). One thread per 8x8 tile.
// Consecutive threads = consecutive gj so both the row-wise float4 loads and
// the per-channel scalar stores are wave-coalesced.

#define BS   8
#define HW   1024
#define GH   128
#define GW   128
#define NIMG 64

__global__ __launch_bounds__(256) void dct2d_kernel(
        const float* __restrict__ x,
        const float* __restrict__ A,
        float* __restrict__ out) {
    __shared__ float sA[64];
    const int tid = threadIdx.x;
    if (tid < 64) sA[tid] = A[tid];
    __syncthreads();

    const int id  = blockIdx.x * 256 + tid;   // [0, 64*128*128)
    const int n   = id >> 14;                 // / (128*128)
    const int rem = id & 16383;
    const int gi  = rem >> 7;                 // / 128
    const int gj  = rem & 127;

    const float* xp = x + (size_t)n * (HW * HW) + (size_t)(gi * BS) * HW + gj * BS;

    // Stage 1: t[k][j] = sum_l block[k][l] * A[j][l]   (block @ A^T)
    float t[8][8];
    #pragma unroll
    for (int k = 0; k < 8; ++k) {
        const float4 lo = *(const float4*)(xp + (size_t)k * HW);
        const float4 hi = *(const float4*)(xp + (size_t)k * HW + 4);
        const float row[8] = {lo.x, lo.y, lo.z, lo.w, hi.x, hi.y, hi.z, hi.w};
        #pragma unroll
        for (int j = 0; j < 8; ++j) {
            float s = 0.0f;
            #pragma unroll
            for (int l = 0; l < 8; ++l) s += row[l] * sA[j * 8 + l];
            t[k][j] = s;
        }
    }

    // Stage 2: coeff[i][j] = sum_k A[i][k] * t[k][j]   (A @ t), store as we go.
    float* op = out + (size_t)n * (64 * GH * GW) + (size_t)gi * GW + gj;
    #pragma unroll
    for (int i = 0; i < 8; ++i) {
        #pragma unroll
        for (int j = 0; j < 8; ++j) {
            float s = 0.0f;
            #pragma unroll
            for (int k = 0; k < 8; ++k) s += sA[i * 8 + k] * t[k][j];
            op[(size_t)(i * 8 + j) * (GH * GW)] = s;
        }
    }
}

extern "C" void kernel_launch(void* const* d_in, const int* in_sizes, int n_in,
                              void* d_out, int out_size, void* d_ws, size_t ws_size,
                              hipStream_t stream) {
    const float* x = (const float*)d_in[0];
    const float* A = (const float*)d_in[1];
    float* out     = (float*)d_out;

    const int total_threads = NIMG * GH * GW;       // 1,048,576
    const int block = 256;
    const int grid  = total_threads / block;        // 4096 (exact)
    dct2d_kernel<<<grid, block, 0, stream>>>(x, A, out);
}